// Round 7
// baseline (789.125 us; speedup 1.0000x reference)
//
#include <hip/hip_runtime.h>

static constexpr int NXC   = 128;              // cells per axis
static constexpr int NPTS  = 100000;
static constexpr int NCH   = 8;
static constexpr int TS    = 8;                // tile cells/axis
static constexpr int NT    = 16;               // tiles/axis
static constexpr int NTILES = NT * NT * NT;    // 4096
static constexpr int REC   = 20;               // floats per global particle record
static constexpr int RS    = 11;               // region nodes/axis (8 + 3)
static constexpr int HALO  = 14;               // candidate cells/axis (8 + 6)
static constexpr int CMAX  = 256;              // max candidates (E≈131, +11σ)

// P3M order-4 per-axis weights, x in [-1/2, 1/2]
__device__ __forceinline__ void axis_weights(float x, float w[4]) {
    float x2 = x * x, x3 = x2 * x;
    const float c = 1.0f / 48.0f;
    w[0] = c * (1.0f  - 6.0f  * x + 12.0f * x2 - 8.0f  * x3);
    w[1] = c * (23.0f - 30.0f * x - 12.0f * x2 + 24.0f * x3);
    w[2] = c * (23.0f + 30.0f * x - 12.0f * x2 - 24.0f * x3);
    w[3] = c * (1.0f  + 6.0f  * x + 12.0f * x2 + 8.0f  * x3);
}

// Mesh-scaled fractional coords (identical FP sequence in every kernel).
__device__ __forceinline__ void mesh_coords(const float* __restrict__ pos,
                                            const float* __restrict__ cell,
                                            int p, float& rx, float& ry, float& rz) {
    float a = cell[0], b = cell[1], c = cell[2];
    float d = cell[3], e = cell[4], f = cell[5];
    float g = cell[6], h = cell[7], i9 = cell[8];
    float c00 = e * i9 - f * h, c01 = f * g - d * i9, c02 = d * h - e * g;
    float c10 = c * h - b * i9, c11 = a * i9 - c * g, c12 = b * g - a * h;
    float c20 = b * f - c * e,  c21 = c * d - a * f,  c22 = a * e - b * d;
    float det = a * c00 + b * c01 + c * c02;
    float s = 128.0f / det;
    float p0 = pos[p * 3 + 0], p1 = pos[p * 3 + 1], p2 = pos[p * 3 + 2];
    rx = s * (p0 * c00 + p1 * c01 + p2 * c02);
    ry = s * (p0 * c10 + p1 * c11 + p2 * c12);
    rz = s * (p0 * c20 + p1 * c21 + p2 * c22);
}

__global__ __launch_bounds__(256) void hist_k(const float* __restrict__ pos,
                                              const float* __restrict__ cell,
                                              int* __restrict__ counts) {
    int p = blockIdx.x * 256 + threadIdx.x;
    if (p >= NPTS) return;
    float rx, ry, rz;
    mesh_coords(pos, cell, p, rx, ry, rz);
    int ix = ((int)floorf(rx)) & (NXC - 1);
    int iy = ((int)floorf(ry)) & (NXC - 1);
    int iz = ((int)floorf(rz)) & (NXC - 1);
    int tile = ((ix >> 3) * NT + (iy >> 3)) * NT + (iz >> 3);
    atomicAdd(counts + tile, 1);
}

// exclusive prefix sum over 4096 counts -> offsets[0..4096]
__global__ __launch_bounds__(256) void scan_k(const int* __restrict__ counts,
                                              int* __restrict__ offsets) {
    __shared__ int sc[256];
    int tid = threadIdx.x;
    int c[16];
    int s = 0;
    #pragma unroll
    for (int j = 0; j < 16; ++j) { c[j] = counts[tid * 16 + j]; s += c[j]; }
    sc[tid] = s;
    __syncthreads();
    for (int d = 1; d < 256; d <<= 1) {
        int v = (tid >= d) ? sc[tid - d] : 0;
        __syncthreads();
        sc[tid] += v;
        __syncthreads();
    }
    int run = sc[tid] - s;
    #pragma unroll
    for (int j = 0; j < 16; ++j) { offsets[tid * 16 + j] = run; run += c[j]; }
    if (tid == 255) offsets[NTILES] = run;
}

// Bin particles by tile; emit packed cell, original pid, and a 5-float4 record:
// [wx0..3][wy0..3][wz0..3][ch0..3][ch4..7]
__global__ __launch_bounds__(256) void reorder_k(const float* __restrict__ pos,
                                                 const float* __restrict__ pw,
                                                 const float* __restrict__ cell,
                                                 const int* __restrict__ offsets,
                                                 int* __restrict__ cursor,
                                                 int* __restrict__ scell,
                                                 int* __restrict__ spid,
                                                 float* __restrict__ srec) {
    int p = blockIdx.x * 256 + threadIdx.x;
    if (p >= NPTS) return;
    float rx, ry, rz;
    mesh_coords(pos, cell, p, rx, ry, rz);
    float fx = floorf(rx), fy = floorf(ry), fz = floorf(rz);
    int ix = ((int)fx) & (NXC - 1), iy = ((int)fy) & (NXC - 1), iz = ((int)fz) & (NXC - 1);
    int tile = ((ix >> 3) * NT + (iy >> 3)) * NT + (iz >> 3);
    int slot = atomicAdd(cursor + tile, 1);
    int idx = offsets[tile] + slot;
    scell[idx] = ix | (iy << 8) | (iz << 16);
    spid[idx] = p;
    float wx[4], wy[4], wz[4];
    axis_weights(rx - fx - 0.5f, wx);
    axis_weights(ry - fy - 0.5f, wy);
    axis_weights(rz - fz - 0.5f, wz);
    float4* r = reinterpret_cast<float4*>(srec) + (size_t)idx * 5;
    r[0] = make_float4(wx[0], wx[1], wx[2], wx[3]);
    r[1] = make_float4(wy[0], wy[1], wy[2], wy[3]);
    r[2] = make_float4(wz[0], wz[1], wz[2], wz[3]);
    const float4* pw4 = reinterpret_cast<const float4*>(pw + (size_t)p * NCH);
    r[3] = pw4[0];
    r[4] = pw4[1];
}

// One block per tile. Scatter all 14^3-halo candidates into an LDS region
// (11^3 nodes x 4 ch per pass), then gather own particles from LDS.
// Lane layout per 16-lane unit: lane = (k<<2)|c  ->  k = z-stencil slot,
// c = channel; every LDS atomic/read of a unit spans 16 consecutive floats.
__global__ __launch_bounds__(256) void fused_k(const int* __restrict__ offsets,
                                               const int* __restrict__ scell,
                                               const int* __restrict__ spid,
                                               const float* __restrict__ srec,
                                               float* __restrict__ out) {
    __shared__ float region[RS * RS * RS * 4];   // 21,296 B
    __shared__ __align__(16) float cw[CMAX * 12]; // 12,288 B (wx,wy,wz per cand)
    __shared__ int clc[CMAX];                     // packed local cell
    __shared__ int cgi[CMAX];                     // global sorted index
    __shared__ int nb0[27];
    __shared__ int nbase[28];
    __shared__ int ncand;

    int b = blockIdx.x;
    int tx = b >> 8, ty = (b >> 4) & 15, tz = b & 15;
    int tid = threadIdx.x;
    int lane = tid & 63;
    int begin = offsets[b], end = offsets[b + 1];
    int nown = end - begin;
    if (nown == 0) return;  // uniform; nothing to output from this block

    if (tid < 27) {
        int ox = tid / 9 - 1, oy = (tid / 3) % 3 - 1, oz = tid % 3 - 1;
        int nt = ((((tx + ox) & 15) * NT + ((ty + oy) & 15)) * NT) + ((tz + oz) & 15);
        nb0[tid] = offsets[nt];
        nbase[tid] = offsets[nt + 1] - nb0[tid];
    }
    if (tid == 0) ncand = 0;
    __syncthreads();
    if (tid == 0) {
        int run = 0;
        #pragma unroll
        for (int n = 0; n < 27; ++n) { int c = nbase[n]; nbase[n] = run; run += c; }
        nbase[27] = run;
    }
    __syncthreads();
    int tc = nbase[27];

    // stage filtered halo candidates: local cell + 12 weights
    int base_x = tx * TS - 3, base_y = ty * TS - 3, base_z = tz * TS - 3;
    const float4* recs = reinterpret_cast<const float4*>(srec);
    for (int u0 = 0; u0 < tc; u0 += 256) {
        int u = u0 + tid;
        bool pass = false;
        int i = 0, lcx = 0, lcy = 0, lcz = 0;
        if (u < tc) {
            int lo = 0, hi = 27;
            while (hi - lo > 1) { int mid = (lo + hi) >> 1; if (nbase[mid] <= u) lo = mid; else hi = mid; }
            i = nb0[lo] + (u - nbase[lo]);
            int c = scell[i];
            lcx = ((c & 255) - base_x) & 127;
            lcy = (((c >> 8) & 255) - base_y) & 127;
            lcz = (((c >> 16) & 255) - base_z) & 127;
            pass = lcx < HALO && lcy < HALO && lcz < HALO;
        }
        unsigned long long m = __ballot(pass);
        int kb = 0;
        if (lane == 0 && m) kb = atomicAdd(&ncand, __popcll(m));
        kb = __shfl(kb, 0, 64);
        if (pass) {
            int k = kb + __popcll(m & ((1ull << lane) - 1ull));
            if (k < CMAX) {
                clc[k] = lcx | (lcy << 4) | (lcz << 8);
                cgi[k] = i;
                const float4* r = recs + (size_t)i * 5;
                float4* d = reinterpret_cast<float4*>(cw + k * 12);
                d[0] = r[0]; d[1] = r[1]; d[2] = r[2];
            }
        }
    }
    __syncthreads();
    int nc = min(ncand, CMAX);

    int lk = (tid >> 2) & 3;   // z-stencil slot
    int lc = tid & 3;          // channel within pass
    int unit = tid >> 4;       // 16 units of 16 lanes

    #pragma unroll
    for (int pass = 0; pass < 2; ++pass) {
        int ch_off = pass * 4;
        for (int i2 = tid; i2 < RS * RS * RS * 4; i2 += 256) region[i2] = 0.0f;
        __syncthreads();

        // scatter: unit handles candidates cand = unit, unit+16, ...
        for (int cand = unit; cand < nc; cand += 16) {
            int cc = clc[cand];
            int lcx = cc & 15, lcy = (cc >> 4) & 15, lcz = cc >> 8;
            int lnz = lcz + lk - 3;
            if ((unsigned)lnz < (unsigned)RS) {
                float chv = srec[(size_t)cgi[cand] * REC + 12 + ch_off + lc];
                float vz = cw[cand * 12 + 8 + lk] * chv;
                #pragma unroll
                for (int ij = 0; ij < 16; ++ij) {
                    int i3 = ij >> 2, j3 = ij & 3;
                    int lnx = lcx + i3 - 3, lny = lcy + j3 - 3;
                    if ((unsigned)lnx < (unsigned)RS && (unsigned)lny < (unsigned)RS) {
                        float w = cw[cand * 12 + i3] * cw[cand * 12 + 4 + j3] * vz;
                        atomicAdd(&region[((lnx * RS + lny) * RS + lnz) * 4 + lc], w);
                    }
                }
            }
        }
        __syncthreads();

        // gather own particles from LDS region
        for (int p = unit; p < nown; p += 16) {
            int gidx = begin + p;
            int c = scell[gidx];
            int lcx = c & 7, lcy = (c >> 8) & 7, lcz = (c >> 16) & 7;
            const float4* r = recs + (size_t)gidx * 5;
            float4 wx4 = r[0], wy4 = r[1], wz4 = r[2];
            float wzk = lk == 0 ? wz4.x : lk == 1 ? wz4.y : lk == 2 ? wz4.z : wz4.w;
            int lnz = lcz + lk;  // in [0,10]
            float acc = 0.0f;
            #pragma unroll
            for (int ij = 0; ij < 16; ++ij) {
                int i3 = ij >> 2, j3 = ij & 3;
                float wxi = i3 == 0 ? wx4.x : i3 == 1 ? wx4.y : i3 == 2 ? wx4.z : wx4.w;
                float wyj = j3 == 0 ? wy4.x : j3 == 1 ? wy4.y : j3 == 2 ? wy4.z : wy4.w;
                int lnx = lcx + i3, lny = lcy + j3;
                acc += wxi * wyj * region[((lnx * RS + lny) * RS + lnz) * 4 + lc];
            }
            acc *= wzk;
            acc += __shfl_xor(acc, 4, 64);
            acc += __shfl_xor(acc, 8, 64);
            if (lk == 0) out[(size_t)spid[gidx] * NCH + ch_off + lc] = acc;
        }
        __syncthreads();
    }
}

extern "C" void kernel_launch(void* const* d_in, const int* in_sizes, int n_in,
                              void* d_out, int out_size, void* d_ws, size_t ws_size,
                              hipStream_t stream) {
    const float* pos  = (const float*)d_in[0];
    const float* pw   = (const float*)d_in[1];
    const float* cell = (const float*)d_in[2];
    float* out = (float*)d_out;

    float* srec   = (float*)d_ws;                 // NPTS*20 floats (16B aligned)
    int*   scell  = (int*)(srec + (size_t)NPTS * REC);
    int*   spid   = scell + NPTS;
    int*   counts = spid + NPTS;
    int*   cursor = counts + NTILES;
    int*   offsets = cursor + NTILES;             // NTILES+1

    hipMemsetAsync(counts, 0, 2 * NTILES * sizeof(int), stream);

    int pblocks = (NPTS + 255) / 256;
    hist_k<<<pblocks, 256, 0, stream>>>(pos, cell, counts);
    scan_k<<<1, 256, 0, stream>>>(counts, offsets);
    reorder_k<<<pblocks, 256, 0, stream>>>(pos, pw, cell, offsets, cursor,
                                           scell, spid, srec);
    fused_k<<<NTILES, 256, 0, stream>>>(offsets, scell, spid, srec, out);
}

// Round 8
// 131.413 us; speedup vs baseline: 6.0049x; 6.0049x over previous
//
#include <hip/hip_runtime.h>

static constexpr int NXC   = 128;              // cells per axis
static constexpr int NPTS  = 100000;
static constexpr int NCH   = 8;
static constexpr int TS    = 8;                // tile cells/axis
static constexpr int NT    = 16;               // tiles/axis
static constexpr int NTILES = NT * NT * NT;    // 4096
static constexpr int REC   = 20;               // floats per particle record (5 float4)
static constexpr int CMAX  = 320;              // max candidates per block (E≈131)

// P3M order-4 per-axis weights, x in [-1/2, 1/2]
__device__ __forceinline__ void axis_weights(float x, float w[4]) {
    float x2 = x * x, x3 = x2 * x;
    const float c = 1.0f / 48.0f;
    w[0] = c * (1.0f  - 6.0f  * x + 12.0f * x2 - 8.0f  * x3);
    w[1] = c * (23.0f - 30.0f * x - 12.0f * x2 + 24.0f * x3);
    w[2] = c * (23.0f + 30.0f * x - 12.0f * x2 - 24.0f * x3);
    w[3] = c * (1.0f  + 6.0f  * x + 12.0f * x2 + 8.0f  * x3);
}

// Mesh-scaled fractional coords (identical FP sequence in every kernel).
__device__ __forceinline__ void mesh_coords(const float* __restrict__ pos,
                                            const float* __restrict__ cell,
                                            int p, float& rx, float& ry, float& rz) {
    float a = cell[0], b = cell[1], c = cell[2];
    float d = cell[3], e = cell[4], f = cell[5];
    float g = cell[6], h = cell[7], i9 = cell[8];
    float c00 = e * i9 - f * h, c01 = f * g - d * i9, c02 = d * h - e * g;
    float c10 = c * h - b * i9, c11 = a * i9 - c * g, c12 = b * g - a * h;
    float c20 = b * f - c * e,  c21 = c * d - a * f,  c22 = a * e - b * d;
    float det = a * c00 + b * c01 + c * c02;
    float s = 128.0f / det;
    float p0 = pos[p * 3 + 0], p1 = pos[p * 3 + 1], p2 = pos[p * 3 + 2];
    rx = s * (p0 * c00 + p1 * c01 + p2 * c02);
    ry = s * (p0 * c10 + p1 * c11 + p2 * c12);
    rz = s * (p0 * c20 + p1 * c21 + p2 * c22);
}

__global__ __launch_bounds__(256) void hist_k(const float* __restrict__ pos,
                                              const float* __restrict__ cell,
                                              int* __restrict__ counts) {
    int p = blockIdx.x * 256 + threadIdx.x;
    if (p >= NPTS) return;
    float rx, ry, rz;
    mesh_coords(pos, cell, p, rx, ry, rz);
    int ix = ((int)floorf(rx)) & (NXC - 1);
    int iy = ((int)floorf(ry)) & (NXC - 1);
    int iz = ((int)floorf(rz)) & (NXC - 1);
    int tile = ((ix >> 3) * NT + (iy >> 3)) * NT + (iz >> 3);
    atomicAdd(counts + tile, 1);
}

// exclusive prefix sum over 4096 counts -> offsets[0..4096]
__global__ __launch_bounds__(256) void scan_k(const int* __restrict__ counts,
                                              int* __restrict__ offsets) {
    __shared__ int sc[256];
    int tid = threadIdx.x;
    int c[16];
    int s = 0;
    #pragma unroll
    for (int j = 0; j < 16; ++j) { c[j] = counts[tid * 16 + j]; s += c[j]; }
    sc[tid] = s;
    __syncthreads();
    for (int d = 1; d < 256; d <<= 1) {
        int v = (tid >= d) ? sc[tid - d] : 0;
        __syncthreads();
        sc[tid] += v;
        __syncthreads();
    }
    int run = sc[tid] - s;
    #pragma unroll
    for (int j = 0; j < 16; ++j) { offsets[tid * 16 + j] = run; run += c[j]; }
    if (tid == 255) offsets[NTILES] = run;
}

// Bin particles by tile; emit packed cell, original pid, and a 5-float4 record:
// [wx0..3][wy0..3][wz0..3][ch0..3][ch4..7]
__global__ __launch_bounds__(256) void reorder_k(const float* __restrict__ pos,
                                                 const float* __restrict__ pw,
                                                 const float* __restrict__ cell,
                                                 const int* __restrict__ offsets,
                                                 int* __restrict__ cursor,
                                                 int* __restrict__ scell,
                                                 int* __restrict__ spid,
                                                 float* __restrict__ srec) {
    int p = blockIdx.x * 256 + threadIdx.x;
    if (p >= NPTS) return;
    float rx, ry, rz;
    mesh_coords(pos, cell, p, rx, ry, rz);
    float fx = floorf(rx), fy = floorf(ry), fz = floorf(rz);
    int ix = ((int)fx) & (NXC - 1), iy = ((int)fy) & (NXC - 1), iz = ((int)fz) & (NXC - 1);
    int tile = ((ix >> 3) * NT + (iy >> 3)) * NT + (iz >> 3);
    int slot = atomicAdd(cursor + tile, 1);
    int idx = offsets[tile] + slot;
    scell[idx] = ix | (iy << 8) | (iz << 16);
    spid[idx] = p;
    float wx[4], wy[4], wz[4];
    axis_weights(rx - fx - 0.5f, wx);
    axis_weights(ry - fy - 0.5f, wy);
    axis_weights(rz - fz - 0.5f, wz);
    float4* r = reinterpret_cast<float4*>(srec) + (size_t)idx * 5;
    r[0] = make_float4(wx[0], wx[1], wx[2], wx[3]);
    r[1] = make_float4(wy[0], wy[1], wy[2], wy[3]);
    r[2] = make_float4(wz[0], wz[1], wz[2], wz[3]);
    const float4* pw4 = reinterpret_cast<const float4*>(pw + (size_t)p * NCH);
    r[3] = pw4[0];
    r[4] = pw4[1];
}

// Sx(d) = sum_i wp[i] * wq[i-d], zero outside [0,3]; d in [-3,3].
__device__ __forceinline__ float corr4(float4 wp, float4 wq, int d) {
    float s0 = d == 0 ? wq.x : d == -1 ? wq.y : d == -2 ? wq.z : d == -3 ? wq.w : 0.0f;
    float s1 = d == 1 ? wq.x : d ==  0 ? wq.y : d == -1 ? wq.z : d == -2 ? wq.w : 0.0f;
    float s2 = d == 2 ? wq.x : d ==  1 ? wq.y : d ==  0 ? wq.z : d == -1 ? wq.w : 0.0f;
    float s3 = d == 3 ? wq.x : d ==  2 ? wq.y : d ==  1 ? wq.z : d ==  0 ? wq.w : 0.0f;
    return wp.x * s0 + wp.y * s1 + wp.z * s2 + wp.w * s3;
}

// One block per tile. Stage only filtered candidate cells+indices in LDS
// (2.6 KB); eval reads candidate records from L2. 8 lanes per owned particle,
// register accumulation, shfl reduce.
__global__ __launch_bounds__(256) void pair_k(const int* __restrict__ offsets,
                                              const int* __restrict__ scell,
                                              const int* __restrict__ spid,
                                              const float* __restrict__ srec,
                                              float* __restrict__ out) {
    __shared__ int ccell[CMAX];
    __shared__ int cidx[CMAX];
    __shared__ int nb0[27];
    __shared__ int nbase[28];
    __shared__ int ncand;

    int b = blockIdx.x;
    int tx = b >> 8, ty = (b >> 4) & 15, tz = b & 15;
    int tid = threadIdx.x;
    int lane = tid & 63;
    int begin = offsets[b], end = offsets[b + 1];
    int nown = end - begin;
    if (nown == 0) return;  // uniform; no barrier crossed yet

    if (tid < 27) {
        int ox = tid / 9 - 1, oy = (tid / 3) % 3 - 1, oz = tid % 3 - 1;
        int nt = ((((tx + ox) & 15) * NT + ((ty + oy) & 15)) * NT) + ((tz + oz) & 15);
        nb0[tid] = offsets[nt];
        nbase[tid] = offsets[nt + 1] - nb0[tid];
    }
    if (tid == 0) ncand = 0;
    __syncthreads();
    if (tid == 0) {
        int run = 0;
        #pragma unroll
        for (int n = 0; n < 27; ++n) { int c = nbase[n]; nbase[n] = run; run += c; }
        nbase[27] = run;
    }
    __syncthreads();
    int tc = nbase[27];

    // stage filtered candidates (cell + index only)
    int base_x = tx * TS - 3, base_y = ty * TS - 3, base_z = tz * TS - 3;
    for (int u0 = 0; u0 < tc; u0 += 256) {
        int u = u0 + tid;
        bool pass = false;
        int i = 0, c = 0;
        if (u < tc) {
            int lo = 0, hi = 27;
            while (hi - lo > 1) { int mid = (lo + hi) >> 1; if (nbase[mid] <= u) lo = mid; else hi = mid; }
            i = nb0[lo] + (u - nbase[lo]);
            c = scell[i];
            pass = (((c & 255)         - base_x) & 127) < 14
                && ((((c >> 8) & 255)  - base_y) & 127) < 14
                && ((((c >> 16) & 255) - base_z) & 127) < 14;
        }
        unsigned long long m = __ballot(pass);
        int kb = 0;
        if (lane == 0 && m) kb = atomicAdd(&ncand, __popcll(m));
        kb = __shfl(kb, 0, 64);
        if (pass) {
            int k = kb + __popcll(m & ((1ull << lane) - 1ull));
            if (k < CMAX) { ccell[k] = c; cidx[k] = i; }
        }
    }
    __syncthreads();
    int nc = min(ncand, CMAX);

    // gather: 8 lanes per owned particle, register accumulation
    const float4* recs = reinterpret_cast<const float4*>(srec);
    int sub = tid & 7, pg = tid >> 3;  // 32 groups of 8
    for (int p0 = 0; p0 < nown; p0 += 32) {
        int p = p0 + pg;
        bool live = p < nown;
        float acc[8] = {0, 0, 0, 0, 0, 0, 0, 0};
        if (live) {
            int pc = scell[begin + p];
            int px = pc & 255, py = (pc >> 8) & 255, pz = (pc >> 16) & 255;
            const float4* r = recs + (size_t)(begin + p) * 5;
            float4 pxw = r[0], pyw = r[1], pzw = r[2];
            for (int j = sub; j < nc; j += 8) {
                int qc = ccell[j];
                int dx = (((qc & 255) - px) & 127);         if (dx > 63) dx -= 128;
                int dy = ((((qc >> 8) & 255) - py) & 127);  if (dy > 63) dy -= 128;
                int dz = ((((qc >> 16) & 255) - pz) & 127); if (dz > 63) dz -= 128;
                if ((unsigned)(dx + 3) <= 6u && (unsigned)(dy + 3) <= 6u &&
                    (unsigned)(dz + 3) <= 6u) {
                    const float4* q = recs + (size_t)cidx[j] * 5;
                    float4 qxw = q[0], qyw = q[1], qzw = q[2];
                    float S = corr4(pxw, qxw, dx) * corr4(pyw, qyw, dy) *
                              corr4(pzw, qzw, dz);
                    float4 ch0 = q[3], ch1 = q[4];
                    acc[0] += S * ch0.x; acc[1] += S * ch0.y;
                    acc[2] += S * ch0.z; acc[3] += S * ch0.w;
                    acc[4] += S * ch1.x; acc[5] += S * ch1.y;
                    acc[6] += S * ch1.z; acc[7] += S * ch1.w;
                }
            }
        }
        // reduce across the 8 lanes of the group
        #pragma unroll
        for (int m = 1; m <= 4; m <<= 1) {
            #pragma unroll
            for (int c = 0; c < 8; ++c) acc[c] += __shfl_xor(acc[c], m, 64);
        }
        if (live && sub == 0) {
            int pid = spid[begin + p];
            float4* o = reinterpret_cast<float4*>(out + (size_t)pid * NCH);
            o[0] = make_float4(acc[0], acc[1], acc[2], acc[3]);
            o[1] = make_float4(acc[4], acc[5], acc[6], acc[7]);
        }
    }
}

extern "C" void kernel_launch(void* const* d_in, const int* in_sizes, int n_in,
                              void* d_out, int out_size, void* d_ws, size_t ws_size,
                              hipStream_t stream) {
    const float* pos  = (const float*)d_in[0];
    const float* pw   = (const float*)d_in[1];
    const float* cell = (const float*)d_in[2];
    float* out = (float*)d_out;

    float* srec   = (float*)d_ws;                 // NPTS*20 floats (16B aligned)
    int*   scell  = (int*)(srec + (size_t)NPTS * REC);
    int*   spid   = scell + NPTS;
    int*   counts = spid + NPTS;
    int*   cursor = counts + NTILES;
    int*   offsets = cursor + NTILES;             // NTILES+1

    hipMemsetAsync(counts, 0, 2 * NTILES * sizeof(int), stream);

    int pblocks = (NPTS + 255) / 256;
    hist_k<<<pblocks, 256, 0, stream>>>(pos, cell, counts);
    scan_k<<<1, 256, 0, stream>>>(counts, offsets);
    reorder_k<<<pblocks, 256, 0, stream>>>(pos, pw, cell, offsets, cursor,
                                           scell, spid, srec);
    pair_k<<<NTILES, 256, 0, stream>>>(offsets, scell, spid, srec, out);
}

// Round 9
// 82.364 us; speedup vs baseline: 9.5809x; 1.5955x over previous
//
#include <hip/hip_runtime.h>

static constexpr int NXC   = 128;              // cells per axis
static constexpr int NPTS  = 100000;
static constexpr int NCH   = 8;
static constexpr int TS    = 8;                // tile cells/axis
static constexpr int NT    = 16;               // tiles/axis
static constexpr int NTILES = NT * NT * NT;    // 4096
static constexpr int REC   = 20;               // floats per particle record (5 float4)
static constexpr int CMAX  = 320;              // max candidates per block (E≈131)
static constexpr int OMAX  = 80;               // max owned per block (E≈24.4, +11σ)
static constexpr int NMAX  = 56;               // max neighbors per particle (E≈16.4, +10σ)

// SWAR field constants for packed (x | y<<10 | z<<20) cell math
static constexpr int M1   = 1 | (1 << 10) | (1 << 20);
static constexpr int M7   = 7 * M1;
static constexpr int M8   = 8 | (8 << 10) | (8 << 20);
static constexpr int M120 = 120 | (120 << 10) | (120 << 20);

// P3M order-4 per-axis weights, x in [-1/2, 1/2]
__device__ __forceinline__ void axis_weights(float x, float w[4]) {
    float x2 = x * x, x3 = x2 * x;
    const float c = 1.0f / 48.0f;
    w[0] = c * (1.0f  - 6.0f  * x + 12.0f * x2 - 8.0f  * x3);
    w[1] = c * (23.0f - 30.0f * x - 12.0f * x2 + 24.0f * x3);
    w[2] = c * (23.0f + 30.0f * x - 12.0f * x2 - 24.0f * x3);
    w[3] = c * (1.0f  + 6.0f  * x + 12.0f * x2 + 8.0f  * x3);
}

// Mesh-scaled fractional coords (identical FP sequence in every kernel).
__device__ __forceinline__ void mesh_coords(const float* __restrict__ pos,
                                            const float* __restrict__ cell,
                                            int p, float& rx, float& ry, float& rz) {
    float a = cell[0], b = cell[1], c = cell[2];
    float d = cell[3], e = cell[4], f = cell[5];
    float g = cell[6], h = cell[7], i9 = cell[8];
    float c00 = e * i9 - f * h, c01 = f * g - d * i9, c02 = d * h - e * g;
    float c10 = c * h - b * i9, c11 = a * i9 - c * g, c12 = b * g - a * h;
    float c20 = b * f - c * e,  c21 = c * d - a * f,  c22 = a * e - b * d;
    float det = a * c00 + b * c01 + c * c02;
    float s = 128.0f / det;
    float p0 = pos[p * 3 + 0], p1 = pos[p * 3 + 1], p2 = pos[p * 3 + 2];
    rx = s * (p0 * c00 + p1 * c01 + p2 * c02);
    ry = s * (p0 * c10 + p1 * c11 + p2 * c12);
    rz = s * (p0 * c20 + p1 * c21 + p2 * c22);
}

__global__ __launch_bounds__(256) void hist_k(const float* __restrict__ pos,
                                              const float* __restrict__ cell,
                                              int* __restrict__ counts) {
    int p = blockIdx.x * 256 + threadIdx.x;
    if (p >= NPTS) return;
    float rx, ry, rz;
    mesh_coords(pos, cell, p, rx, ry, rz);
    int ix = ((int)floorf(rx)) & (NXC - 1);
    int iy = ((int)floorf(ry)) & (NXC - 1);
    int iz = ((int)floorf(rz)) & (NXC - 1);
    int tile = ((ix >> 3) * NT + (iy >> 3)) * NT + (iz >> 3);
    atomicAdd(counts + tile, 1);
}

// exclusive prefix sum over 4096 counts -> offsets[0..4096]
__global__ __launch_bounds__(256) void scan_k(const int* __restrict__ counts,
                                              int* __restrict__ offsets) {
    __shared__ int sc[256];
    int tid = threadIdx.x;
    int c[16];
    int s = 0;
    #pragma unroll
    for (int j = 0; j < 16; ++j) { c[j] = counts[tid * 16 + j]; s += c[j]; }
    sc[tid] = s;
    __syncthreads();
    for (int d = 1; d < 256; d <<= 1) {
        int v = (tid >= d) ? sc[tid - d] : 0;
        __syncthreads();
        sc[tid] += v;
        __syncthreads();
    }
    int run = sc[tid] - s;
    #pragma unroll
    for (int j = 0; j < 16; ++j) { offsets[tid * 16 + j] = run; run += c[j]; }
    if (tid == 255) offsets[NTILES] = run;
}

// Bin particles by tile; emit packed cell (x|y<<10|z<<20), original pid, and
// a 5-float4 record: [wx0..3][wy0..3][wz0..3][ch0..3][ch4..7]
__global__ __launch_bounds__(256) void reorder_k(const float* __restrict__ pos,
                                                 const float* __restrict__ pw,
                                                 const float* __restrict__ cell,
                                                 const int* __restrict__ offsets,
                                                 int* __restrict__ cursor,
                                                 int* __restrict__ scell,
                                                 int* __restrict__ spid,
                                                 float* __restrict__ srec) {
    int p = blockIdx.x * 256 + threadIdx.x;
    if (p >= NPTS) return;
    float rx, ry, rz;
    mesh_coords(pos, cell, p, rx, ry, rz);
    float fx = floorf(rx), fy = floorf(ry), fz = floorf(rz);
    int ix = ((int)fx) & (NXC - 1), iy = ((int)fy) & (NXC - 1), iz = ((int)fz) & (NXC - 1);
    int tile = ((ix >> 3) * NT + (iy >> 3)) * NT + (iz >> 3);
    int slot = atomicAdd(cursor + tile, 1);
    int idx = offsets[tile] + slot;
    scell[idx] = ix | (iy << 10) | (iz << 20);
    spid[idx] = p;
    float wx[4], wy[4], wz[4];
    axis_weights(rx - fx - 0.5f, wx);
    axis_weights(ry - fy - 0.5f, wy);
    axis_weights(rz - fz - 0.5f, wz);
    float4* r = reinterpret_cast<float4*>(srec) + (size_t)idx * 5;
    r[0] = make_float4(wx[0], wx[1], wx[2], wx[3]);
    r[1] = make_float4(wy[0], wy[1], wy[2], wy[3]);
    r[2] = make_float4(wz[0], wz[1], wz[2], wz[3]);
    const float4* pw4 = reinterpret_cast<const float4*>(pw + (size_t)p * NCH);
    r[3] = pw4[0];
    r[4] = pw4[1];
}

// Sx(d) = sum_i wp[i] * wq[i-d], zero outside [0,3]; d in [-3,3].
__device__ __forceinline__ float corr4(float4 wp, float4 wq, int d) {
    float s0 = d == 0 ? wq.x : d == -1 ? wq.y : d == -2 ? wq.z : d == -3 ? wq.w : 0.0f;
    float s1 = d == 1 ? wq.x : d ==  0 ? wq.y : d == -1 ? wq.z : d == -2 ? wq.w : 0.0f;
    float s2 = d == 2 ? wq.x : d ==  1 ? wq.y : d ==  0 ? wq.z : d == -1 ? wq.w : 0.0f;
    float s3 = d == 3 ? wq.x : d ==  2 ? wq.y : d ==  1 ? wq.z : d ==  0 ? wq.w : 0.0f;
    return wp.x * s0 + wp.y * s1 + wp.z * s2 + wp.w * s3;
}

// One block per tile. Stage filtered candidate cells+indices (2.6 KB LDS).
// Phase A: SWAR filter builds per-owned-particle neighbor lists (d packed).
// Phase B: 8 lanes per particle walk its list densely; register accumulation,
// shfl reduce, direct write. Records read from L2 (srec ~8 MB, L2-resident).
__global__ __launch_bounds__(256) void pair_k(const int* __restrict__ offsets,
                                              const int* __restrict__ scell,
                                              const int* __restrict__ spid,
                                              const float* __restrict__ srec,
                                              float* __restrict__ out) {
    __shared__ int ccell[CMAX];
    __shared__ int cidx[CMAX];
    __shared__ int nlist[OMAX * NMAX];   // 17.9 KB
    __shared__ int cnt[OMAX];
    __shared__ int nb0[27];
    __shared__ int nbase[28];
    __shared__ int ncand;

    int b = blockIdx.x;
    int tx = b >> 8, ty = (b >> 4) & 15, tz = b & 15;
    int tid = threadIdx.x;
    int lane = tid & 63;
    int begin = offsets[b], end = offsets[b + 1];
    int nown = end - begin;
    if (nown == 0) return;  // uniform; no barrier crossed yet
    if (nown > OMAX) nown = OMAX;  // statistically unreachable

    if (tid < 27) {
        int ox = tid / 9 - 1, oy = (tid / 3) % 3 - 1, oz = tid % 3 - 1;
        int nt = ((((tx + ox) & 15) * NT + ((ty + oy) & 15)) * NT) + ((tz + oz) & 15);
        nb0[tid] = offsets[nt];
        nbase[tid] = offsets[nt + 1] - nb0[tid];
    }
    if (tid == 0) ncand = 0;
    for (int i = tid; i < OMAX; i += 256) cnt[i] = 0;
    __syncthreads();
    if (tid == 0) {
        int run = 0;
        #pragma unroll
        for (int n = 0; n < 27; ++n) { int c = nbase[n]; nbase[n] = run; run += c; }
        nbase[27] = run;
    }
    __syncthreads();
    int tc = nbase[27];

    // stage filtered candidates (cell + index only)
    int base_x = tx * TS - 3, base_y = ty * TS - 3, base_z = tz * TS - 3;
    for (int u0 = 0; u0 < tc; u0 += 256) {
        int u = u0 + tid;
        bool pass = false;
        int i = 0, c = 0;
        if (u < tc) {
            int lo = 0, hi = 27;
            while (hi - lo > 1) { int mid = (lo + hi) >> 1; if (nbase[mid] <= u) lo = mid; else hi = mid; }
            i = nb0[lo] + (u - nbase[lo]);
            c = scell[i];
            pass = (((c & 1023)         - base_x) & 127) < 14
                && ((((c >> 10) & 1023) - base_y) & 127) < 14
                && ((((c >> 20) & 1023) - base_z) & 127) < 14;
        }
        unsigned long long m = __ballot(pass);
        int kb = 0;
        if (lane == 0 && m) kb = atomicAdd(&ncand, __popcll(m));
        kb = __shfl(kb, 0, 64);
        if (pass) {
            int k = kb + __popcll(m & ((1ull << lane) - 1ull));
            if (k < CMAX) { ccell[k] = c; cidx[k] = i; }
        }
    }
    __syncthreads();
    int nc = min(ncand, CMAX);

    int sub = tid & 7, pg = tid >> 3;  // 32 groups of 8 lanes

    // --- phase A: build per-particle neighbor lists via SWAR filter ---
    for (int p0 = 0; p0 < nown; p0 += 32) {
        int p = p0 + pg;
        bool live = p < nown;
        int bias = 0;
        if (live) {
            int pc = scell[begin + p];
            int px = pc & 1023, py = (pc >> 10) & 1023, pz = (pc >> 20) & 1023;
            bias = ((131 - px) & 127) | (((131 - py) & 127) << 10)
                 | (((131 - pz) & 127) << 20);
        }
        for (int j0 = 0; j0 < nc; j0 += 8) {
            int j = j0 + sub;
            if (live && j < nc) {
                int t = ccell[j] + bias;
                // pass  <=>  per-field (t mod 128) in [0,6]
                if (((t & M120) == 0) && ((((t & M7) + M1) & M8) == 0)) {
                    int ent = j | ((t & 7) << 9) | (((t >> 10) & 7) << 12)
                                | (((t >> 20) & 7) << 15);
                    int slot = atomicAdd(&cnt[p], 1);
                    if (slot < NMAX) nlist[p * NMAX + slot] = ent;
                }
            }
        }
    }
    __syncthreads();

    // --- phase B: dense eval over each particle's list ---
    const float4* recs = reinterpret_cast<const float4*>(srec);
    for (int p0 = 0; p0 < nown; p0 += 32) {
        int p = p0 + pg;
        bool live = p < nown;
        int n = 0;
        float4 pxw, pyw, pzw;
        if (live) {
            n = min(cnt[p], NMAX);
            const float4* r = recs + (size_t)(begin + p) * 5;
            pxw = r[0]; pyw = r[1]; pzw = r[2];
        }
        float acc[8] = {0, 0, 0, 0, 0, 0, 0, 0};
        for (int s = sub; s < n; s += 8) {
            int ent = nlist[p * NMAX + s];
            int j = ent & 511;
            int dx = ((ent >> 9) & 7) - 3;
            int dy = ((ent >> 12) & 7) - 3;
            int dz = ((ent >> 15) & 7) - 3;
            const float4* q = recs + (size_t)cidx[j] * 5;
            float4 qxw = q[0], qyw = q[1], qzw = q[2];
            float S = corr4(pxw, qxw, dx) * corr4(pyw, qyw, dy) * corr4(pzw, qzw, dz);
            float4 ch0 = q[3], ch1 = q[4];
            acc[0] += S * ch0.x; acc[1] += S * ch0.y;
            acc[2] += S * ch0.z; acc[3] += S * ch0.w;
            acc[4] += S * ch1.x; acc[5] += S * ch1.y;
            acc[6] += S * ch1.z; acc[7] += S * ch1.w;
        }
        // reduce across the 8 lanes of the group
        #pragma unroll
        for (int m = 1; m <= 4; m <<= 1) {
            #pragma unroll
            for (int c = 0; c < 8; ++c) acc[c] += __shfl_xor(acc[c], m, 64);
        }
        if (live && sub == 0) {
            int pid = spid[begin + p];
            float4* o = reinterpret_cast<float4*>(out + (size_t)pid * NCH);
            o[0] = make_float4(acc[0], acc[1], acc[2], acc[3]);
            o[1] = make_float4(acc[4], acc[5], acc[6], acc[7]);
        }
    }
}

extern "C" void kernel_launch(void* const* d_in, const int* in_sizes, int n_in,
                              void* d_out, int out_size, void* d_ws, size_t ws_size,
                              hipStream_t stream) {
    const float* pos  = (const float*)d_in[0];
    const float* pw   = (const float*)d_in[1];
    const float* cell = (const float*)d_in[2];
    float* out = (float*)d_out;

    float* srec   = (float*)d_ws;                 // NPTS*20 floats (16B aligned)
    int*   scell  = (int*)(srec + (size_t)NPTS * REC);
    int*   spid   = scell + NPTS;
    int*   counts = spid + NPTS;
    int*   cursor = counts + NTILES;
    int*   offsets = cursor + NTILES;             // NTILES+1

    hipMemsetAsync(counts, 0, 2 * NTILES * sizeof(int), stream);

    int pblocks = (NPTS + 255) / 256;
    hist_k<<<pblocks, 256, 0, stream>>>(pos, cell, counts);
    scan_k<<<1, 256, 0, stream>>>(counts, offsets);
    reorder_k<<<pblocks, 256, 0, stream>>>(pos, pw, cell, offsets, cursor,
                                           scell, spid, srec);
    pair_k<<<NTILES, 256, 0, stream>>>(offsets, scell, spid, srec, out);
}